// Round 4
// baseline (123.218 us; speedup 1.0000x reference)
//
#include <hip/hip_runtime.h>
#include <math.h>

#define SH_C0 0.28209479177387814f
#define SH_C1 0.4886025119029199f
#define NEARP 0.01f
#define FARP 1e10f
#define LOWPASS 0.3f
#define ALPHA_MIN (1.0f/255.0f)
#define ALPHA_MAX 0.999f

// ws layout (floats): sorted AoS @ 0, stride 12 per gaussian:
//   [mx,my,A,B | C,op,r,g | b,dep,rad,0]
// (N <= 1024 for this problem; fused kernel keeps everything in registers/LDS)

// Single block, 1024 threads: per-gaussian preprocess in registers, depth key
// to LDS, stable rank-sort via LDS count, direct register->sorted scatter.
__global__ void __launch_bounds__(1024) gs_prep_sort(
        const float* __restrict__ means3d,
        const float* __restrict__ quats,
        const float* __restrict__ scales,
        const float* __restrict__ opacities,
        const float* __restrict__ sh,
        const float* __restrict__ c2w,
        const float* __restrict__ K,
        int N, float* __restrict__ sorted)
{
    __shared__ float keys[1024];
    int i = threadIdx.x;

    // viewmat = rigid inverse of camtoworld (row-major 4x4)
    float t0 = c2w[3], t1 = c2w[7], t2 = c2w[11];
    float Rw[3][3];
    Rw[0][0] = c2w[0]; Rw[0][1] = c2w[4]; Rw[0][2] = c2w[8];
    Rw[1][0] = c2w[1]; Rw[1][1] = c2w[5]; Rw[1][2] = c2w[9];
    Rw[2][0] = c2w[2]; Rw[2][1] = c2w[6]; Rw[2][2] = c2w[10];
    float tw0 = -(Rw[0][0]*t0 + Rw[0][1]*t1 + Rw[0][2]*t2);
    float tw1 = -(Rw[1][0]*t0 + Rw[1][1]*t1 + Rw[1][2]*t2);
    float tw2 = -(Rw[2][0]*t0 + Rw[2][1]*t1 + Rw[2][2]*t2);
    float fx = K[0], fy = K[4], cx = K[2], cy = K[5];

    float rec[12];
    float key = INFINITY;
    bool active = (i < N);

    if (active) {
        float m0 = means3d[3*i+0], m1 = means3d[3*i+1], m2 = means3d[3*i+2];
        float x = Rw[0][0]*m0 + Rw[0][1]*m1 + Rw[0][2]*m2 + tw0;
        float y = Rw[1][0]*m0 + Rw[1][1]*m1 + Rw[1][2]*m2 + tw1;
        float z = Rw[2][0]*m0 + Rw[2][1]*m1 + Rw[2][2]*m2 + tw2;

        bool valid = (z > NEARP) && (z < FARP);
        float zs = valid ? z : 1.0f;
        float mean2x = fx * x / zs + cx;
        float mean2y = fy * y / zs + cy;

        float qw = quats[4*i+0], qx = quats[4*i+1], qy = quats[4*i+2], qz = quats[4*i+3];
        float qn = rsqrtf(qw*qw + qx*qx + qy*qy + qz*qz);
        qw *= qn; qx *= qn; qy *= qn; qz *= qn;
        float Rg[3][3];
        Rg[0][0] = 1.f - 2.f*(qy*qy + qz*qz); Rg[0][1] = 2.f*(qx*qy - qw*qz); Rg[0][2] = 2.f*(qx*qz + qw*qy);
        Rg[1][0] = 2.f*(qx*qy + qw*qz); Rg[1][1] = 1.f - 2.f*(qx*qx + qz*qz); Rg[1][2] = 2.f*(qy*qz - qw*qx);
        Rg[2][0] = 2.f*(qx*qz - qw*qy); Rg[2][1] = 2.f*(qy*qz + qw*qx); Rg[2][2] = 1.f - 2.f*(qx*qx + qy*qy);

        float sx = scales[3*i+0], sy = scales[3*i+1], sz = scales[3*i+2];
        float M[3][3];
        #pragma unroll
        for (int r = 0; r < 3; ++r) { M[r][0] = Rg[r][0]*sx; M[r][1] = Rg[r][1]*sy; M[r][2] = Rg[r][2]*sz; }

        float c3[3][3];
        #pragma unroll
        for (int r = 0; r < 3; ++r)
            #pragma unroll
            for (int c = 0; c < 3; ++c)
                c3[r][c] = M[r][0]*M[c][0] + M[r][1]*M[c][1] + M[r][2]*M[c][2];

        float Tm[3][3];
        #pragma unroll
        for (int r = 0; r < 3; ++r)
            #pragma unroll
            for (int c = 0; c < 3; ++c)
                Tm[r][c] = Rw[r][0]*c3[0][c] + Rw[r][1]*c3[1][c] + Rw[r][2]*c3[2][c];
        float cc[3][3];
        #pragma unroll
        for (int r = 0; r < 3; ++r)
            #pragma unroll
            for (int c = 0; c < 3; ++c)
                cc[r][c] = Tm[r][0]*Rw[c][0] + Tm[r][1]*Rw[c][1] + Tm[r][2]*Rw[c][2];

        float j00 = fx / zs;
        float j02 = -fx * x / (zs * zs);
        float j11 = fy / zs;
        float j12 = -fy * y / (zs * zs);
        float v00 = cc[0][0]*j00 + cc[0][2]*j02;
        float v02 = cc[2][0]*j00 + cc[2][2]*j02;
        float v10 = cc[0][1]*j11 + cc[0][2]*j12;
        float v12 = cc[2][1]*j11 + cc[2][2]*j12;
        float c2d00 = j00*v00 + j02*v02;
        float c2d01 = j00*v10 + j02*v12;
        float c2d11 = j11*(cc[1][1]*j11 + cc[1][2]*j12) + j12*v12;

        float a = c2d00 + LOWPASS;
        float b = c2d01;
        float c = c2d11 + LOWPASS;
        float det = a*c - b*b;
        valid = valid && (det > 0.f);
        float dets = (det > 0.f) ? det : 1.0f;
        float inv_det = 1.0f / dets;
        float conA = c * inv_det;
        float conB = -b * inv_det;
        float conC = a * inv_det;

        // SH degree-1 color
        float d0 = m0 - t0, d1 = m1 - t1, d2 = m2 - t2;
        float nrm = sqrtf(d0*d0 + d1*d1 + d2*d2);
        float inv_n = 1.0f / fmaxf(nrm, 1e-8f);
        float dxn = d0 * inv_n, dyn = d1 * inv_n, dzn = d2 * inv_n;
        const float* shi = sh + 12*i;
        float col0 = fmaxf(SH_C0*shi[0] - SH_C1*dyn*shi[3] + SH_C1*dzn*shi[6] - SH_C1*dxn*shi[9]  + 0.5f, 0.f);
        float col1 = fmaxf(SH_C0*shi[1] - SH_C1*dyn*shi[4] + SH_C1*dzn*shi[7] - SH_C1*dxn*shi[10] + 0.5f, 0.f);
        float col2 = fmaxf(SH_C0*shi[2] - SH_C1*dyn*shi[5] + SH_C1*dzn*shi[8] - SH_C1*dxn*shi[11] + 0.5f, 0.f);

        float opa = 1.0f / (1.0f + __expf(-opacities[i]));
        float opv = valid ? opa : 0.0f;

        // conservative cull radius: outside rad, alpha < 1/255 provably
        float lmax = 0.5f*(a + c) + sqrtf(0.25f*(a - c)*(a - c) + b*b);
        float rad = 0.f;
        if (valid && opv * 255.f > 1.0f) {
            float smax = logf(255.f * opv);
            rad = sqrtf(fmaxf(2.f * smax * lmax, 0.f)) * 1.02f + 0.1f;
        }

        rec[0] = mean2x; rec[1] = mean2y; rec[2] = conA; rec[3] = conB;
        rec[4] = conC;   rec[5] = opv;    rec[6] = col0; rec[7] = col1;
        rec[8] = col2;   rec[9] = z;      rec[10] = rad; rec[11] = 0.f;
        key = valid ? z : INFINITY;
    }

    keys[i] = key;
    __syncthreads();

    if (!active) return;

    // stable rank over all keys (LDS broadcast float4 reads)
    int rank = 0;
    const float4* keys4 = (const float4*)keys;
    int n4 = N >> 2;
    for (int j4 = 0; j4 < n4; ++j4) {
        float4 kv = keys4[j4];
        int base = j4 << 2;
        rank += (int)((kv.x < key) || (kv.x == key && base + 0 < i));
        rank += (int)((kv.y < key) || (kv.y == key && base + 1 < i));
        rank += (int)((kv.z < key) || (kv.z == key && base + 2 < i));
        rank += (int)((kv.w < key) || (kv.w == key && base + 3 < i));
    }
    for (int j = n4 << 2; j < N; ++j) {
        float kj = keys[j];
        rank += (int)((kj < key) || (kj == key && j < i));
    }

    float4* o = (float4*)(sorted + rank*12);
    o[0] = make_float4(rec[0], rec[1], rec[2], rec[3]);
    o[1] = make_float4(rec[4], rec[5], rec[6], rec[7]);
    o[2] = make_float4(rec[8], rec[9], rec[10], rec[11]);
}

// 256 threads = 4 waves per block; one 8x8 tile per wave. All sorted records
// staged in LDS once per block; binning + compositing are LDS-only.
__global__ void __launch_bounds__(256) gs_render(const float* __restrict__ sorted,
                                                 const int* __restrict__ wp,
                                                 const int* __restrict__ hp,
                                                 int N, float* __restrict__ out)
{
    __shared__ float srec[1024 * 12];              // 48 KB: all sorted records
    __shared__ unsigned short list[4][1024];       // 8 KB: per-wave tile list
    int t = threadIdx.x;
    int wave = t >> 6, lane = t & 63;
    int W = *wp, H = *hp;
    int tiles_x = (W + 7) >> 3, tiles_y = (H + 7) >> 3;
    int total_tiles = tiles_x * tiles_y;
    int WH = W * H;

    // stage all records (N*3 float4), coalesced
    {
        const float4* src = (const float4*)sorted;
        float4* dst = (float4*)srec;
        int n4 = N * 3;
        for (int i = t; i < n4; i += 256) dst[i] = src[i];
    }
    __syncthreads();   // only barrier; waves independent below

    const float4* rec4 = (const float4*)srec;

    for (int tile = blockIdx.x * 4 + wave; tile < total_tiles; tile += gridDim.x * 4) {
        int tx = tile % tiles_x, ty = tile / tiles_x;
        float tx0 = (float)(tx << 3) + 0.5f, tx1 = (float)(tx << 3) + 7.5f;
        float ty0 = (float)(ty << 3) + 0.5f, ty1 = (float)(ty << 3) + 7.5f;

        // binning: order-preserving wave compaction, LDS reads only
        int count = 0;
        for (int b0 = 0; b0 < N; b0 += 64) {
            int g = b0 + lane;
            float mx  = srec[12*g + 0];
            float my  = srec[12*g + 1];
            float rad = srec[12*g + 10];
            bool hit = (rad > 0.f)
                    && (mx - rad <= tx1) && (mx + rad >= tx0)
                    && (my - rad <= ty1) && (my + rad >= ty0);
            unsigned long long mask = __ballot(hit);
            int pre = __popcll(mask & ((1ull << lane) - 1ull));
            if (hit) list[wave][count + pre] = (unsigned short)g;
            count += (int)__popcll(mask);
        }

        int px_i = (tx << 3) + (lane & 7);
        int py_i = (ty << 3) + (lane >> 3);
        bool live = (px_i < W) && (py_i < H);
        float px = (float)px_i + 0.5f, py = (float)py_i + 0.5f;

        float T = live ? 1.0f : 0.0f;
        float cr = 0.f, cg = 0.f, cb = 0.f, acc = 0.f, ed = 0.f;

        for (int j = 0; j < count; ++j) {
            if (((j & 15) == 0) && __all(T < 1e-6f)) break;
            int gi = list[wave][j];
            float4 g0 = rec4[gi*3 + 0];   // mx,my,A,B  (broadcast)
            float4 g1 = rec4[gi*3 + 1];   // C,op,r,g
            float4 g2 = rec4[gi*3 + 2];   // b,dep,rad,0
            float dx = px - g0.x, dy = py - g0.y;
            float sigma = 0.5f*(g0.z*dx*dx + g1.x*dy*dy) + g0.w*dx*dy;
            float alpha = fminf(g1.y * __expf(-sigma), ALPHA_MAX);
            if (sigma >= 0.f && alpha >= ALPHA_MIN) {
                float w = alpha * T;
                cr = fmaf(w, g1.z, cr);
                cg = fmaf(w, g1.w, cg);
                cb = fmaf(w, g2.x, cb);
                acc += w;
                ed = fmaf(w, g2.y, ed);
                T *= (1.0f - alpha);
            }
        }

        if (live) {
            int p = py_i * W + px_i;
            ((float4*)out)[p] = make_float4(cr, cg, cb, ed / fmaxf(acc, 1e-10f));
            out[WH*4 + p] = acc;
        }
    }
}

extern "C" void kernel_launch(void* const* d_in, const int* in_sizes, int n_in,
                              void* d_out, int out_size, void* d_ws, size_t ws_size,
                              hipStream_t stream) {
    const float* means3d   = (const float*)d_in[0];
    const float* quats     = (const float*)d_in[1];
    const float* scales    = (const float*)d_in[2];
    const float* opacities = (const float*)d_in[3];
    const float* sh        = (const float*)d_in[4];
    const float* c2w       = (const float*)d_in[5];
    const float* K         = (const float*)d_in[6];
    const int*   wp        = (const int*)d_in[7];
    const int*   hp        = (const int*)d_in[8];

    int N = in_sizes[0] / 3;   // 1024 for this problem (fits single-block sort)
    float* sorted = (float*)d_ws;  // 12N floats

    gs_prep_sort<<<1, 1024, 0, stream>>>(
        means3d, quats, scales, opacities, sh, c2w, K, N, sorted);

    int WH = out_size / 5;             // 4 color channels + 1 alpha per pixel
    int nblocks = (WH + 255) / 256;    // 4 tiles (waves) per block
    gs_render<<<nblocks, 256, 0, stream>>>(sorted, wp, hp, N, (float*)d_out);
}

// Round 5
// 109.527 us; speedup vs baseline: 1.1250x; 1.1250x over previous
//
#include <hip/hip_runtime.h>
#include <math.h>

#define SH_C0 0.28209479177387814f
#define SH_C1 0.4886025119029199f
#define NEARP 0.01f
#define FARP 1e10f
#define LOWPASS 0.3f
#define ALPHA_MIN (1.0f/255.0f)
#define ALPHA_MAX 0.999f

// ws layout (floats):
//   fields 0..10 : SoA arrays of length N: mx,my,conA,conB,conC,op,r,g,b,dep,radius
//   key          : @ 11N  (depth, INF when invalid)
//   sorted AoS   : @ 12N, stride 12: [mx,my,A,B | C,op,r,g | b,dep,rad,0]

__global__ void __launch_bounds__(64) gs_preprocess(
        const float* __restrict__ means3d,
        const float* __restrict__ quats,
        const float* __restrict__ scales,
        const float* __restrict__ opacities,
        const float* __restrict__ sh,
        const float* __restrict__ c2w,
        const float* __restrict__ K,
        int N, float* __restrict__ ws)
{
    int i = blockIdx.x * blockDim.x + threadIdx.x;
    if (i >= N) return;

    // viewmat = rigid inverse of camtoworld (row-major 4x4)
    float t0 = c2w[3], t1 = c2w[7], t2 = c2w[11];
    float Rw[3][3];
    Rw[0][0] = c2w[0]; Rw[0][1] = c2w[4]; Rw[0][2] = c2w[8];
    Rw[1][0] = c2w[1]; Rw[1][1] = c2w[5]; Rw[1][2] = c2w[9];
    Rw[2][0] = c2w[2]; Rw[2][1] = c2w[6]; Rw[2][2] = c2w[10];
    float tw0 = -(Rw[0][0]*t0 + Rw[0][1]*t1 + Rw[0][2]*t2);
    float tw1 = -(Rw[1][0]*t0 + Rw[1][1]*t1 + Rw[1][2]*t2);
    float tw2 = -(Rw[2][0]*t0 + Rw[2][1]*t1 + Rw[2][2]*t2);
    float fx = K[0], fy = K[4], cx = K[2], cy = K[5];

    float m0 = means3d[3*i+0], m1 = means3d[3*i+1], m2 = means3d[3*i+2];
    float x = Rw[0][0]*m0 + Rw[0][1]*m1 + Rw[0][2]*m2 + tw0;
    float y = Rw[1][0]*m0 + Rw[1][1]*m1 + Rw[1][2]*m2 + tw1;
    float z = Rw[2][0]*m0 + Rw[2][1]*m1 + Rw[2][2]*m2 + tw2;

    bool valid = (z > NEARP) && (z < FARP);
    float zs = valid ? z : 1.0f;
    float mean2x = fx * x / zs + cx;
    float mean2y = fy * y / zs + cy;

    float qw = quats[4*i+0], qx = quats[4*i+1], qy = quats[4*i+2], qz = quats[4*i+3];
    float qn = rsqrtf(qw*qw + qx*qx + qy*qy + qz*qz);
    qw *= qn; qx *= qn; qy *= qn; qz *= qn;
    float Rg[3][3];
    Rg[0][0] = 1.f - 2.f*(qy*qy + qz*qz); Rg[0][1] = 2.f*(qx*qy - qw*qz); Rg[0][2] = 2.f*(qx*qz + qw*qy);
    Rg[1][0] = 2.f*(qx*qy + qw*qz); Rg[1][1] = 1.f - 2.f*(qx*qx + qz*qz); Rg[1][2] = 2.f*(qy*qz - qw*qx);
    Rg[2][0] = 2.f*(qx*qz - qw*qy); Rg[2][1] = 2.f*(qy*qz + qw*qx); Rg[2][2] = 1.f - 2.f*(qx*qx + qy*qy);

    float sx = scales[3*i+0], sy = scales[3*i+1], sz = scales[3*i+2];
    float M[3][3];
    #pragma unroll
    for (int r = 0; r < 3; ++r) { M[r][0] = Rg[r][0]*sx; M[r][1] = Rg[r][1]*sy; M[r][2] = Rg[r][2]*sz; }

    float c3[3][3];
    #pragma unroll
    for (int r = 0; r < 3; ++r)
        #pragma unroll
        for (int c = 0; c < 3; ++c)
            c3[r][c] = M[r][0]*M[c][0] + M[r][1]*M[c][1] + M[r][2]*M[c][2];

    float Tm[3][3];
    #pragma unroll
    for (int r = 0; r < 3; ++r)
        #pragma unroll
        for (int c = 0; c < 3; ++c)
            Tm[r][c] = Rw[r][0]*c3[0][c] + Rw[r][1]*c3[1][c] + Rw[r][2]*c3[2][c];
    float cc[3][3];
    #pragma unroll
    for (int r = 0; r < 3; ++r)
        #pragma unroll
        for (int c = 0; c < 3; ++c)
            cc[r][c] = Tm[r][0]*Rw[c][0] + Tm[r][1]*Rw[c][1] + Tm[r][2]*Rw[c][2];

    float j00 = fx / zs;
    float j02 = -fx * x / (zs * zs);
    float j11 = fy / zs;
    float j12 = -fy * y / (zs * zs);
    float v00 = cc[0][0]*j00 + cc[0][2]*j02;
    float v02 = cc[2][0]*j00 + cc[2][2]*j02;
    float v10 = cc[0][1]*j11 + cc[0][2]*j12;
    float v12 = cc[2][1]*j11 + cc[2][2]*j12;
    float c2d00 = j00*v00 + j02*v02;
    float c2d01 = j00*v10 + j02*v12;
    float c2d11 = j11*(cc[1][1]*j11 + cc[1][2]*j12) + j12*v12;

    float a = c2d00 + LOWPASS;
    float b = c2d01;
    float c = c2d11 + LOWPASS;
    float det = a*c - b*b;
    valid = valid && (det > 0.f);
    float dets = (det > 0.f) ? det : 1.0f;
    float inv_det = 1.0f / dets;
    float conA = c * inv_det;
    float conB = -b * inv_det;
    float conC = a * inv_det;

    // SH degree-1 color
    float d0 = m0 - t0, d1 = m1 - t1, d2 = m2 - t2;
    float nrm = sqrtf(d0*d0 + d1*d1 + d2*d2);
    float inv_n = 1.0f / fmaxf(nrm, 1e-8f);
    float dxn = d0 * inv_n, dyn = d1 * inv_n, dzn = d2 * inv_n;
    const float* shi = sh + 12*i;
    float col0 = fmaxf(SH_C0*shi[0] - SH_C1*dyn*shi[3] + SH_C1*dzn*shi[6] - SH_C1*dxn*shi[9]  + 0.5f, 0.f);
    float col1 = fmaxf(SH_C0*shi[1] - SH_C1*dyn*shi[4] + SH_C1*dzn*shi[7] - SH_C1*dxn*shi[10] + 0.5f, 0.f);
    float col2 = fmaxf(SH_C0*shi[2] - SH_C1*dyn*shi[5] + SH_C1*dzn*shi[8] - SH_C1*dxn*shi[11] + 0.5f, 0.f);

    float opa = 1.0f / (1.0f + __expf(-opacities[i]));
    float opv = valid ? opa : 0.0f;

    // conservative cull radius: outside rad, alpha < 1/255 provably
    float lmax = 0.5f*(a + c) + sqrtf(0.25f*(a - c)*(a - c) + b*b);
    float rad = 0.f;
    if (valid && opv * 255.f > 1.0f) {
        float smax = logf(255.f * opv);
        rad = sqrtf(fmaxf(2.f * smax * lmax, 0.f)) * 1.02f + 0.1f;
    }

    ws[0*N + i] = mean2x;
    ws[1*N + i] = mean2y;
    ws[2*N + i] = conA;
    ws[3*N + i] = conB;
    ws[4*N + i] = conC;
    ws[5*N + i] = opv;
    ws[6*N + i] = col0;
    ws[7*N + i] = col1;
    ws[8*N + i] = col2;
    ws[9*N + i] = z;
    ws[10*N + i] = rad;
    ws[11*N + i] = valid ? z : INFINITY;  // sort key
}

// rank sort spread over 16 CUs: each block stages all keys to LDS; each
// thread computes its gaussian's stable rank and scatters its record.
__global__ void __launch_bounds__(64) gs_rank(const float* __restrict__ ws,
                                              float* __restrict__ sorted, int N)
{
    __shared__ float keys[1024];
    int t = threadIdx.x;
    int gid = blockIdx.x * 64 + t;
    for (int i = t; i < N; i += 64) keys[i] = ws[11*N + i];
    __syncthreads();
    if (gid >= N) return;
    float k = keys[gid];
    int rank = 0;
    const float4* keys4 = (const float4*)keys;
    for (int j4 = 0; j4 < (N >> 2); ++j4) {
        float4 kv = keys4[j4];          // LDS broadcast read
        int base = j4 << 2;
        rank += (int)((kv.x < k) || (kv.x == k && base + 0 < gid));
        rank += (int)((kv.y < k) || (kv.y == k && base + 1 < gid));
        rank += (int)((kv.z < k) || (kv.z == k && base + 2 < gid));
        rank += (int)((kv.w < k) || (kv.w == k && base + 3 < gid));
    }
    float* o = sorted + rank*12;
    o[0]  = ws[0*N+gid];  // mx
    o[1]  = ws[1*N+gid];  // my
    o[2]  = ws[2*N+gid];  // A
    o[3]  = ws[3*N+gid];  // B
    o[4]  = ws[4*N+gid];  // C
    o[5]  = ws[5*N+gid];  // op
    o[6]  = ws[6*N+gid];  // r
    o[7]  = ws[7*N+gid];  // g
    o[8]  = ws[8*N+gid];  // b
    o[9]  = ws[9*N+gid];  // dep
    o[10] = ws[10*N+gid]; // rad
    o[11] = 0.f;
}

// 256 threads = 4 waves per block; one 8x8 tile per wave. All sorted records
// staged in LDS once per block; binning + compositing are LDS-only.
__global__ void __launch_bounds__(256) gs_render(const float* __restrict__ sorted,
                                                 const int* __restrict__ wp,
                                                 const int* __restrict__ hp,
                                                 int N, float* __restrict__ out)
{
    __shared__ float srec[1024 * 12];              // 48 KB: all sorted records
    __shared__ unsigned short list[4][1024];       // 8 KB: per-wave tile list
    int t = threadIdx.x;
    int wave = t >> 6, lane = t & 63;
    int W = *wp, H = *hp;
    int tiles_x = (W + 7) >> 3, tiles_y = (H + 7) >> 3;
    int total_tiles = tiles_x * tiles_y;
    int WH = W * H;

    // stage all records (N*3 float4), coalesced
    {
        const float4* src = (const float4*)sorted;
        float4* dst = (float4*)srec;
        int n4 = N * 3;
        for (int i = t; i < n4; i += 256) dst[i] = src[i];
    }
    __syncthreads();   // only barrier; waves independent below

    const float4* rec4 = (const float4*)srec;

    for (int tile = blockIdx.x * 4 + wave; tile < total_tiles; tile += gridDim.x * 4) {
        int tx = tile % tiles_x, ty = tile / tiles_x;
        float tx0 = (float)(tx << 3) + 0.5f, tx1 = (float)(tx << 3) + 7.5f;
        float ty0 = (float)(ty << 3) + 0.5f, ty1 = (float)(ty << 3) + 7.5f;

        // binning: order-preserving wave compaction, LDS reads only
        int count = 0;
        for (int b0 = 0; b0 < N; b0 += 64) {
            int g = b0 + lane;
            float mx  = srec[12*g + 0];
            float my  = srec[12*g + 1];
            float rad = srec[12*g + 10];
            bool hit = (rad > 0.f)
                    && (mx - rad <= tx1) && (mx + rad >= tx0)
                    && (my - rad <= ty1) && (my + rad >= ty0);
            unsigned long long mask = __ballot(hit);
            int pre = __popcll(mask & ((1ull << lane) - 1ull));
            if (hit) list[wave][count + pre] = (unsigned short)g;
            count += (int)__popcll(mask);
        }

        int px_i = (tx << 3) + (lane & 7);
        int py_i = (ty << 3) + (lane >> 3);
        bool live = (px_i < W) && (py_i < H);
        float px = (float)px_i + 0.5f, py = (float)py_i + 0.5f;

        float T = live ? 1.0f : 0.0f;
        float cr = 0.f, cg = 0.f, cb = 0.f, acc = 0.f, ed = 0.f;

        for (int j = 0; j < count; ++j) {
            if (((j & 15) == 0) && __all(T < 1e-6f)) break;
            int gi = list[wave][j];
            float4 g0 = rec4[gi*3 + 0];   // mx,my,A,B  (broadcast)
            float4 g1 = rec4[gi*3 + 1];   // C,op,r,g
            float4 g2 = rec4[gi*3 + 2];   // b,dep,rad,0
            float dx = px - g0.x, dy = py - g0.y;
            float sigma = 0.5f*(g0.z*dx*dx + g1.x*dy*dy) + g0.w*dx*dy;
            float alpha = fminf(g1.y * __expf(-sigma), ALPHA_MAX);
            if (sigma >= 0.f && alpha >= ALPHA_MIN) {
                float w = alpha * T;
                cr = fmaf(w, g1.z, cr);
                cg = fmaf(w, g1.w, cg);
                cb = fmaf(w, g2.x, cb);
                acc += w;
                ed = fmaf(w, g2.y, ed);
                T *= (1.0f - alpha);
            }
        }

        if (live) {
            int p = py_i * W + px_i;
            ((float4*)out)[p] = make_float4(cr, cg, cb, ed / fmaxf(acc, 1e-10f));
            out[WH*4 + p] = acc;
        }
    }
}

extern "C" void kernel_launch(void* const* d_in, const int* in_sizes, int n_in,
                              void* d_out, int out_size, void* d_ws, size_t ws_size,
                              hipStream_t stream) {
    const float* means3d   = (const float*)d_in[0];
    const float* quats     = (const float*)d_in[1];
    const float* scales    = (const float*)d_in[2];
    const float* opacities = (const float*)d_in[3];
    const float* sh        = (const float*)d_in[4];
    const float* c2w       = (const float*)d_in[5];
    const float* K         = (const float*)d_in[6];
    const int*   wp        = (const int*)d_in[7];
    const int*   hp        = (const int*)d_in[8];

    int N = in_sizes[0] / 3;
    float* ws = (float*)d_ws;
    float* sorted = ws + 12 * N;   // 12N floats

    int nb = (N + 63) / 64;        // 16 blocks at N=1024 -> 16 CUs
    gs_preprocess<<<nb, 64, 0, stream>>>(
        means3d, quats, scales, opacities, sh, c2w, K, N, ws);
    gs_rank<<<nb, 64, 0, stream>>>(ws, sorted, N);

    int WH = out_size / 5;             // 4 color channels + 1 alpha per pixel
    int nblocks = (WH + 255) / 256;    // 4 tiles (waves) per block
    gs_render<<<nblocks, 256, 0, stream>>>(sorted, wp, hp, N, (float*)d_out);
}